// Round 2
// baseline (850.660 us; speedup 1.0000x reference)
//
#include <hip/hip_runtime.h>

// Problem: CausalSelfAttention  B=2, T=2048, C=768, H=12, hs=64
// Round 2: dtype-robust version. A detector kernel decides at runtime whether
// the input tensors are bf16 (mode 0) or fp32 (mode 1); dtype-dependent
// kernels are launched in both flavors and self-select via a flag in d_ws.

#define BB 2
#define TT 2048
#define CC 768
#define C3 2304
#define HH 12
#define DD 64
#define MM 4096   // B*T

typedef unsigned short u16;
typedef unsigned int u32;

__device__ __forceinline__ float u2f(u16 u) {
    union { u32 i; float f; } c; c.i = ((u32)u) << 16; return c.f;
}
__device__ __forceinline__ u16 f2u(float f) {
    union { float f; u32 i; } c; c.f = f;
    u32 x = c.i;
    return (u16)((x + 0x7FFFu + ((x >> 16) & 1u)) >> 16);  // RNE
}

// ---------------------------------------------------------------------------
// Detector: view x as raw u16 words. Genuine bf16 N(0,1) data never has
// exponent 0xFF; fp32 data reinterpreted as u16 has ~0.4% such words in the
// low halves. flag = 1 -> inputs are fp32.
// ---------------------------------------------------------------------------
__global__ void detect_kernel(const u16* __restrict__ x, int nscan,
                              int* __restrict__ flag)
{
    __shared__ int found;
    if (threadIdx.x == 0) found = 0;
    __syncthreads();
    int local = 0;
    for (int i = threadIdx.x; i < nscan; i += 256) {
        if ((x[i] & 0x7F80u) == 0x7F80u) local = 1;
    }
    if (local) atomicOr(&found, 1);
    __syncthreads();
    if (threadIdx.x == 0) *flag = found ? 1 : 0;
}

// ---------------------------------------------------------------------------
// GEMM: out[M,N] = A[M,K] @ B[K,N] + bias[N], fp32 accumulate.
// AM/BM: input dtype mode of A / B+bias (0=bf16, 1=fp32). OM: output mode.
// 64x64 block tile, BK=16, 256 threads, 4x4 micro-tile.
// ---------------------------------------------------------------------------
template <int AM, int BM, int OM>
__global__ __launch_bounds__(256)
void gemm_bias(const void* __restrict__ Av, const void* __restrict__ Bv,
               const void* __restrict__ biasv, void* __restrict__ outv,
               int M, int N, int K, const int* __restrict__ flag, int expect)
{
    if (*flag != expect) return;

    __shared__ float As[16][68];   // [k][m]
    __shared__ float Bs[16][68];   // [k][n]

    const int t = threadIdx.x;
    const int tx = t & 15, ty = t >> 4;
    const int m0 = blockIdx.y * 64;
    const int n0 = blockIdx.x * 64;

    const int am = t >> 2;          // 0..63
    const int ak = (t & 3) << 2;    // 0,4,8,12
    const int bk = t >> 4;          // 0..15
    const int bn = (t & 15) << 2;   // 0..60

    float acc[4][4];
    #pragma unroll
    for (int i = 0; i < 4; ++i)
        #pragma unroll
        for (int j = 0; j < 4; ++j) acc[i][j] = 0.f;

    for (int k0 = 0; k0 < K; k0 += 16) {
        float a0, a1, a2, a3, b0, b1, b2, b3;
        if constexpr (AM == 0) {
            const u16* A = (const u16*)Av;
            ushort4 v = *(const ushort4*)(A + (size_t)(m0 + am) * K + ak + k0);
            a0 = u2f(v.x); a1 = u2f(v.y); a2 = u2f(v.z); a3 = u2f(v.w);
        } else {
            const float* A = (const float*)Av;
            float4 v = *(const float4*)(A + (size_t)(m0 + am) * K + ak + k0);
            a0 = v.x; a1 = v.y; a2 = v.z; a3 = v.w;
        }
        if constexpr (BM == 0) {
            const u16* B = (const u16*)Bv;
            ushort4 v = *(const ushort4*)(B + (size_t)(bk + k0) * N + n0 + bn);
            b0 = u2f(v.x); b1 = u2f(v.y); b2 = u2f(v.z); b3 = u2f(v.w);
        } else {
            const float* B = (const float*)Bv;
            float4 v = *(const float4*)(B + (size_t)(bk + k0) * N + n0 + bn);
            b0 = v.x; b1 = v.y; b2 = v.z; b3 = v.w;
        }
        As[ak + 0][am] = a0;
        As[ak + 1][am] = a1;
        As[ak + 2][am] = a2;
        As[ak + 3][am] = a3;
        *(float4*)&Bs[bk][bn] = make_float4(b0, b1, b2, b3);
        __syncthreads();

        #pragma unroll
        for (int k = 0; k < 16; ++k) {
            float a[4], b4[4];
            #pragma unroll
            for (int i = 0; i < 4; ++i) a[i] = As[k][ty * 4 + i];
            #pragma unroll
            for (int j = 0; j < 4; ++j) b4[j] = Bs[k][tx * 4 + j];
            #pragma unroll
            for (int i = 0; i < 4; ++i)
                #pragma unroll
                for (int j = 0; j < 4; ++j)
                    acc[i][j] += a[i] * b4[j];
        }
        __syncthreads();
    }

    #pragma unroll
    for (int i = 0; i < 4; ++i) {
        const int m = m0 + ty * 4 + i;
        #pragma unroll
        for (int j = 0; j < 4; ++j) {
            const int n = n0 + tx * 4 + j;
            float bv;
            if constexpr (BM == 0) bv = u2f(((const u16*)biasv)[n]);
            else                   bv = ((const float*)biasv)[n];
            float v = acc[i][j] + bv;
            if constexpr (OM == 0) ((u16*)outv)[(size_t)m * N + n] = f2u(v);
            else                   ((float*)outv)[(size_t)m * N + n] = v;
        }
    }
}

// ---------------------------------------------------------------------------
// Flash-style causal attention. qkv bf16 [B,T,3C]; yatt bf16 [B,T,C]
// (head transpose fused into the store). Mode-independent.
// One block per (64-row q-tile, head, batch); 32-key tiles; online softmax.
// ---------------------------------------------------------------------------
__global__ __launch_bounds__(256)
void attn_kernel(const u16* __restrict__ qkv, u16* __restrict__ yatt)
{
    __shared__ float Qs[64][65];   // [d][row]  (transposed, pre-scaled by 1/8)
    __shared__ float Ks[64][33];   // [d][key]  (transposed)
    __shared__ float Vs[32][68];   // [key][d]
    __shared__ float Ps[64][36];   // [row][key]

    const int t = threadIdx.x;
    const int tx = t & 15, ty = t >> 4;
    const int qt = blockIdx.x, h = blockIdx.y, b = blockIdx.z;
    const int q0 = qt * 64;

    // ---- load Q tile (scaled), transposed into LDS ----
    {
        const int row = t >> 2;          // 0..63
        const int d0 = (t & 3) << 4;     // 0,16,32,48
        const u16* qp = qkv + ((size_t)(b * TT + q0 + row)) * C3 + h * DD + d0;
        #pragma unroll
        for (int i = 0; i < 16; i += 4) {
            ushort4 v = *(const ushort4*)(qp + i);
            Qs[d0 + i + 0][row] = u2f(v.x) * 0.125f;
            Qs[d0 + i + 1][row] = u2f(v.y) * 0.125f;
            Qs[d0 + i + 2][row] = u2f(v.z) * 0.125f;
            Qs[d0 + i + 3][row] = u2f(v.w) * 0.125f;
        }
    }

    float m_i[4], l_i[4], O[4][4];
    #pragma unroll
    for (int i = 0; i < 4; ++i) {
        m_i[i] = -1e30f; l_i[i] = 0.f;
        #pragma unroll
        for (int j = 0; j < 4; ++j) O[i][j] = 0.f;
    }

    const int ktiles = 2 * qt + 2;       // keys 0 .. q0+63
    const int kc = t >> 3;               // 0..31
    const int kd0 = (t & 7) << 3;        // 0..56
    const u16* kbase = qkv + ((size_t)(b * TT + kc)) * C3 + CC + h * DD + kd0;

    for (int kt = 0; kt < ktiles; ++kt) {
        {
            const u16* kp = kbase + (size_t)kt * 32 * C3;
            const u16* vp = kp + CC;
            #pragma unroll
            for (int i = 0; i < 8; i += 4) {
                ushort4 kv = *(const ushort4*)(kp + i);
                Ks[kd0 + i + 0][kc] = u2f(kv.x);
                Ks[kd0 + i + 1][kc] = u2f(kv.y);
                Ks[kd0 + i + 2][kc] = u2f(kv.z);
                Ks[kd0 + i + 3][kc] = u2f(kv.w);
                ushort4 vv = *(const ushort4*)(vp + i);
                Vs[kc][kd0 + i + 0] = u2f(vv.x);
                Vs[kc][kd0 + i + 1] = u2f(vv.y);
                Vs[kc][kd0 + i + 2] = u2f(vv.z);
                Vs[kc][kd0 + i + 3] = u2f(vv.w);
            }
        }
        __syncthreads();

        // ---- S = (Q/8) K^T ----
        float s[4][2];
        #pragma unroll
        for (int i = 0; i < 4; ++i) { s[i][0] = 0.f; s[i][1] = 0.f; }
        #pragma unroll 8
        for (int d = 0; d < 64; ++d) {
            const float b0 = Ks[d][tx * 2 + 0];
            const float b1 = Ks[d][tx * 2 + 1];
            #pragma unroll
            for (int i = 0; i < 4; ++i) {
                const float a = Qs[d][ty * 4 + i];
                s[i][0] += a * b0;
                s[i][1] += a * b1;
            }
        }

        // ---- causal mask + online softmax ----
        const int colbase = kt * 32 + tx * 2;
        float alpha[4];
        #pragma unroll
        for (int i = 0; i < 4; ++i) {
            const int rowg = q0 + ty * 4 + i;
            if (colbase + 0 > rowg) s[i][0] = -1e30f;
            if (colbase + 1 > rowg) s[i][1] = -1e30f;
            float mx = fmaxf(s[i][0], s[i][1]);
            mx = fmaxf(mx, __shfl_xor(mx, 1));
            mx = fmaxf(mx, __shfl_xor(mx, 2));
            mx = fmaxf(mx, __shfl_xor(mx, 4));
            mx = fmaxf(mx, __shfl_xor(mx, 8));       // 16-lane row group
            const float mnew = fmaxf(m_i[i], mx);
            const float a = __expf(m_i[i] - mnew);
            const float p0 = __expf(s[i][0] - mnew);
            const float p1 = __expf(s[i][1] - mnew);
            Ps[ty * 4 + i][tx * 2 + 0] = p0;
            Ps[ty * 4 + i][tx * 2 + 1] = p1;
            float rs = p0 + p1;
            rs += __shfl_xor(rs, 1);
            rs += __shfl_xor(rs, 2);
            rs += __shfl_xor(rs, 4);
            rs += __shfl_xor(rs, 8);
            l_i[i] = l_i[i] * a + rs;
            m_i[i] = mnew;
            alpha[i] = a;
        }
        #pragma unroll
        for (int i = 0; i < 4; ++i)
            #pragma unroll
            for (int j = 0; j < 4; ++j) O[i][j] *= alpha[i];
        __syncthreads();

        // ---- O += P @ V ----
        #pragma unroll 8
        for (int j = 0; j < 32; ++j) {
            const float4 v = *(const float4*)&Vs[j][tx * 4];
            const float p0 = Ps[ty * 4 + 0][j];
            const float p1 = Ps[ty * 4 + 1][j];
            const float p2 = Ps[ty * 4 + 2][j];
            const float p3 = Ps[ty * 4 + 3][j];
            O[0][0] += p0 * v.x; O[0][1] += p0 * v.y; O[0][2] += p0 * v.z; O[0][3] += p0 * v.w;
            O[1][0] += p1 * v.x; O[1][1] += p1 * v.y; O[1][2] += p1 * v.z; O[1][3] += p1 * v.w;
            O[2][0] += p2 * v.x; O[2][1] += p2 * v.y; O[2][2] += p2 * v.z; O[2][3] += p2 * v.w;
            O[3][0] += p3 * v.x; O[3][1] += p3 * v.y; O[3][2] += p3 * v.z; O[3][3] += p3 * v.w;
        }
        __syncthreads();
    }

    // ---- epilogue: normalize, store bf16 in [B,T,C] ----
    #pragma unroll
    for (int i = 0; i < 4; ++i) {
        const float inv = 1.0f / l_i[i];
        const int rowg = q0 + ty * 4 + i;
        u16* op = yatt + ((size_t)(b * TT + rowg)) * CC + h * DD + tx * 4;
        op[0] = f2u(O[i][0] * inv);
        op[1] = f2u(O[i][1] * inv);
        op[2] = f2u(O[i][2] * inv);
        op[3] = f2u(O[i][3] * inv);
    }
}

// ---------------------------------------------------------------------------
extern "C" void kernel_launch(void* const* d_in, const int* in_sizes, int n_in,
                              void* d_out, int out_size, void* d_ws, size_t ws_size,
                              hipStream_t stream)
{
    (void)n_in; (void)out_size; (void)ws_size;

    const void* x      = d_in[0];
    const void* W_attn = d_in[1];
    const void* b_attn = d_in[2];
    const void* W_proj = d_in[3];
    const void* b_proj = d_in[4];

    // workspace layout (25.2 MB + flag)
    u16* qkv  = (u16*)d_ws;                      // [4096,2304] bf16
    u16* yatt = qkv + (size_t)MM * C3;           // [4096,768]  bf16
    int* flag = (int*)(yatt + (size_t)MM * CC);  // 1 int

    int nscan = in_sizes[0] < 65536 ? in_sizes[0] : 65536;
    detect_kernel<<<1, 256, 0, stream>>>((const u16*)x, nscan, flag);

    // 1) qkv = x @ W_attn + b_attn  (bf16 out) — both modes, self-selecting
    gemm_bias<0, 0, 0><<<dim3(C3 / 64, MM / 64), 256, 0, stream>>>(
        x, W_attn, b_attn, (void*)qkv, MM, C3, CC, flag, 0);
    gemm_bias<1, 1, 0><<<dim3(C3 / 64, MM / 64), 256, 0, stream>>>(
        x, W_attn, b_attn, (void*)qkv, MM, C3, CC, flag, 1);

    // 2) causal flash attention (mode-independent)
    attn_kernel<<<dim3(TT / 64, HH, BB), 256, 0, stream>>>(qkv, yatt);

    // 3) out = yatt @ W_proj + b_proj — A is always bf16; B/bias/out per mode
    gemm_bias<0, 0, 0><<<dim3(CC / 64, MM / 64), 256, 0, stream>>>(
        yatt, W_proj, b_proj, d_out, MM, CC, CC, flag, 0);
    gemm_bias<0, 1, 1><<<dim3(CC / 64, MM / 64), 256, 0, stream>>>(
        yatt, W_proj, b_proj, d_out, MM, CC, CC, flag, 1);
}